// Round 5
// baseline (387.712 us; speedup 1.0000x reference)
//
#include <hip/hip_runtime.h>
#include <math.h>

// SRP-PHAT via Chebyshev factorization (degree 32; tail ~1e-7 at z_max=14.67).
// G[bt, p*32+c] = sum_f Xnorm_{re|im}[bt,f,p] * coef_c(w_f*S), then
// Ys[bt,d] = sum_k G[bt,k] * Tt[k,d]. Diagonal mic pairs dropped.
// Round 5: stageA NBT=4 bt/block (coef b128 amortized 4x, normalize straight
// from global, 18 KB LDS, f-split x6 -> 1500 blocks); gemmB 64x128 tile with
// 4x8 acc (VALU-bound inner), K-split x2 -> 672 blocks.

#define F_BINS  513
#define M_TOTAL 1000
#define D_TOTAL 2562
#define D_PAD   2688          // 21 * 128
#define NPAIR   28
#define NC      32
#define K2      (NPAIR * NC)  // 896
#define S_SCALE 4.67f         // |dtau| <= 4.665
#define NBT     4             // bt per stageA block
#define FSPLIT  6             // stageA f-splits
#define KSPB    2             // gemmB K-splits
#define KPS     448           // K2 / KSPB

// ws layout (float offsets); total 8,696,960 floats = 34.8 MB (== round 4)
#define OFF_COEF 0
#define OFF_TT   16512
#define OFF_G    (OFF_TT + (size_t)K2 * D_PAD)            // 2,424,960
#define OFF_GP   (OFF_G + (size_t)M_TOTAL * K2)           // 3,320,960
#define OFF_YS   OFF_GP   // Ysp (2 planes, 5.376M) aliases Gp (6 planes, 5.376M)

__device__ __constant__ int c_ptab[NPAIR] = {1,2,3,4,5,6,7, 9,10,11,12,13,14,
                                             16,17,18,19,20, 22,23,24,25,
                                             27,28,29, 31,32, 34};
__device__ __constant__ int c_i0[NPAIR] = {0,0,0,0,0,0,0, 1,1,1,1,1,1,
                                           2,2,2,2,2, 3,3,3,3, 4,4,4, 5,5, 6};
__device__ __constant__ int c_i1[NPAIR] = {1,2,3,4,5,6,7, 2,3,4,5,6,7,
                                           3,4,5,6,7, 4,5,6,7, 5,6,7, 6,7, 7};

// ---- coefEO[f][32]: c<16 -> cos-coeff a_{2c}(z_f); c>=16 -> sin b_{2c'+1} ---
__global__ void k_coef(float* __restrict__ coefEO) {
    __shared__ double sHC[NC][NC + 1];
    __shared__ double sHS[NC][NC + 1];
    const int f = blockIdx.x;
    const int t = threadIdx.x;          // 32 threads
    const double z = (double)f * (M_PI / 512.0) * (double)S_SCALE;
    double th = M_PI * (t + 0.5) / NC;
    double ct = cos(th);
    double hs, hc;
    sincos(z * ct, &hs, &hc);
    double cp = 1.0, cc = ct, c2 = 2.0 * ct;
    sHC[0][t] = hc;      sHS[0][t] = hs;
    sHC[1][t] = hc * cc; sHS[1][t] = hs * cc;
    for (int n = 2; n < NC; ++n) {
        double cn = c2 * cc - cp;
        cp = cc; cc = cn;
        sHC[n][t] = hc * cn;
        sHS[n][t] = hs * cn;
    }
    __syncthreads();
    const int n = (t < 16) ? 2 * t : 2 * (t - 16) + 1;
    double sum = 0.0;
    if (t < 16) { for (int j = 0; j < NC; ++j) sum += sHC[n][j]; }
    else        { for (int j = 0; j < NC; ++j) sum += sHS[n][j]; }
    double scale = (n == 0) ? (1.0 / NC) : (2.0 / NC);
    coefEO[f * 32 + t] = (float)(sum * scale);
}

// ---- Tt[p*32+c][d]: c<16 -> T_{2c}(u), c>=16 -> T_{2(c-16)+1}(u) -----------
__global__ void k_ttab(const float* __restrict__ taus, float* __restrict__ Tt) {
    const int d = blockIdx.x * 256 + threadIdx.x;
    const int p = blockIdx.y;
    if (d >= D_PAD) return;
    const bool live = d < D_TOTAL;
    const int dd = live ? d : 0;
    const float u = (taus[dd * 8 + c_i0[p]] - taus[dd * 8 + c_i1[p]]) * (1.0f / S_SCALE);
    float* base = Tt + (size_t)p * 32 * D_PAD + d;
    base[0] = live ? 1.f : 0.f;                       // n=0 -> c=0
    base[(size_t)16 * D_PAD] = live ? u : 0.f;        // n=1 -> c=16
    float tp = 1.f, tc = u;
    const float u2 = 2.f * u;
    for (int n = 2; n < NC; ++n) {
        float tn = u2 * tc - tp;
        tp = tc; tc = tn;
        int c = (n & 1) ? 16 + (n >> 1) : (n >> 1);
        base[(size_t)c * D_PAD] = live ? tn : 0.f;
    }
}

// ---- stage A: Gp[split][bt][p*32+c], NBT bt per block, f-split x6 ----------
// thread t: p = t&31 (p>=28 dead), sel = t>>5: sel<4 -> Xr, c0=sel*4;
// sel>=4 -> Xi, c0=16+(sel-4)*4. Loops NBT bt per coef read.
__global__ __launch_bounds__(256) void k_stageA(
    const float* __restrict__ XXs, const float* __restrict__ coefEO,
    float* __restrict__ Gp)
{
    __shared__ float sXn[16][NBT][64];   // [fl][bt][row: re 0..27, im 32..59]
    __shared__ float sC[16][32];
    const int t     = threadIdx.x;
    const int bt0   = blockIdx.x * NBT;
    const int split = blockIdx.y;
    const int fbeg  = (F_BINS * split) / FSPLIT;
    const int fend  = (F_BINS * (split + 1)) / FSPLIT;
    const int p   = t & 31;
    const int sel = t >> 5;
    const bool im = sel >= 4;
    const int row = p + (im ? 32 : 0);
    const int c0  = (sel & 3) * 4 + (im ? 16 : 0);
    float acc[NBT][4] = {};

    for (int fc = fbeg; fc < fend; fc += 16) {
        const int cnt = min(16, fend - fc);
        __syncthreads();   // previous chunk consumed
        for (int e = t; e < cnt * 8; e += 256)      // coef chunk, float4
            *(float4*)&sC[0][e * 4] = *(const float4*)&coefEO[fc * 32 + e * 4];
        for (int e = t; e < NBT * cnt * 28; e += 256) {  // normalize from global
            int pp   = e % 28;
            int rest = e / 28;
            int fl   = rest % cnt;
            int bt   = rest / cnt;
            const float* bp = XXs + ((size_t)(bt0 + bt) * F_BINS + (fc + fl)) * 72;
            int po = c_ptab[pp];
            float xr = bp[po];
            float xi = bp[36 + po];
            float inv = 1.f / (sqrtf(xr * xr + xi * xi) + 1e-20f);
            sXn[fl][bt][pp]      = xr * inv;
            sXn[fl][bt][32 + pp] = xi * inv;
        }
        __syncthreads();
        for (int fl = 0; fl < cnt; ++fl) {
            float4 c4 = *(const float4*)&sC[fl][c0];    // broadcast b128, reused NBT x
            #pragma unroll
            for (int bt = 0; bt < NBT; ++bt) {
                float a = sXn[fl][bt][row];             // conflict-free b32
                acc[bt][0] = fmaf(a, c4.x, acc[bt][0]);
                acc[bt][1] = fmaf(a, c4.y, acc[bt][1]);
                acc[bt][2] = fmaf(a, c4.z, acc[bt][2]);
                acc[bt][3] = fmaf(a, c4.w, acc[bt][3]);
            }
        }
    }
    if (p < NPAIR) {
        float* gsp = Gp + (size_t)split * M_TOTAL * K2;
        #pragma unroll
        for (int bt = 0; bt < NBT; ++bt) {
            float4 v = {acc[bt][0], acc[bt][1], acc[bt][2], acc[bt][3]};
            *(float4*)&gsp[(size_t)(bt0 + bt) * K2 + p * 32 + c0] = v;
        }
    }
}

// ---- reduce the 6 f-split partials ----------------------------------------
__global__ void k_reduceG(const float* __restrict__ Gp, float* __restrict__ G) {
    const int i = blockIdx.x * 256 + threadIdx.x;
    const size_t MK = (size_t)M_TOTAL * K2;
    if (i < (int)MK) {
        float s = 0.f;
        #pragma unroll
        for (int k = 0; k < FSPLIT; ++k) s += Gp[i + k * MK];
        G[i] = s;
    }
}

// ---- stage B: Ysp[split][1000][2688] partial of G @ Tt ---------------------
#define BKB 32
__global__ __launch_bounds__(256) void k_gemmB(
    const float* __restrict__ G, const float* __restrict__ Tt,
    float* __restrict__ Ysp)
{
    __shared__ float sAT[64][33];    // [row][k] — conflict-free both sides
    __shared__ float sB[BKB][132];
    const int t = threadIdx.x;
    const int row0 = blockIdx.x * 64;
    const int col0 = blockIdx.y * 128;
    const int koff = blockIdx.z * KPS;
    const int tx = t & 15;
    const int ty = t >> 4;
    float acc[4][8] = {};

    for (int k0 = 0; k0 < KPS; k0 += BKB) {
        __syncthreads();
        for (int e = t; e < 64 * BKB; e += 256) {   // A: coalesced read, cf write
            int r = e >> 5, kk = e & 31;
            int rg = row0 + r;
            sAT[r][kk] = (rg < M_TOTAL) ? G[(size_t)rg * K2 + koff + k0 + kk] : 0.f;
        }
        for (int e = t; e < 1024; e += 256) {       // B: 32x128 float4
            int kk = e >> 5, cq = e & 31;
            *(float4*)&sB[kk][cq * 4] =
                *(const float4*)&Tt[(size_t)(koff + k0 + kk) * D_PAD + col0 + cq * 4];
        }
        __syncthreads();
        #pragma unroll 8
        for (int kk = 0; kk < BKB; ++kk) {
            float av[4];
            #pragma unroll
            for (int i = 0; i < 4; ++i) av[i] = sAT[ty * 4 + i][kk];
            float4 b0 = *(const float4*)&sB[kk][tx * 8];
            float4 b1 = *(const float4*)&sB[kk][tx * 8 + 4];
            float bv[8] = {b0.x, b0.y, b0.z, b0.w, b1.x, b1.y, b1.z, b1.w};
            #pragma unroll
            for (int i = 0; i < 4; ++i)
                #pragma unroll
                for (int j = 0; j < 8; ++j)
                    acc[i][j] = fmaf(av[i], bv[j], acc[i][j]);
        }
    }
    float* yp = Ysp + (size_t)blockIdx.z * M_TOTAL * D_PAD;
    #pragma unroll
    for (int i = 0; i < 4; ++i) {
        int rg = row0 + ty * 4 + i;
        if (rg >= M_TOTAL) continue;
        float* y = yp + (size_t)rg * D_PAD + col0 + tx * 8;
        float4 v0 = {acc[i][0], acc[i][1], acc[i][2], acc[i][3]};
        float4 v1 = {acc[i][4], acc[i][5], acc[i][6], acc[i][7]};
        *(float4*)&y[0] = v0;
        *(float4*)&y[4] = v1;
    }
}

// ---- argmax over summed K-split partials + doa gather ----------------------
__global__ __launch_bounds__(256) void k_argmax(
    const float* __restrict__ Ysp, const float* __restrict__ doas,
    float* __restrict__ out)
{
    __shared__ float sv[256];
    __shared__ int   si[256];
    const int row = blockIdx.x;
    const int tid = threadIdx.x;
    const float* y0 = Ysp + (size_t)row * D_PAD;
    const float* y1 = y0 + (size_t)M_TOTAL * D_PAD;
    float best = -INFINITY;
    int bi = D_TOTAL;
    for (int d = tid; d < D_TOTAL; d += 256) {
        float v = y0[d] + y1[d];
        if (v > best) { best = v; bi = d; }
    }
    sv[tid] = best; si[tid] = bi;
    __syncthreads();
    for (int s = 128; s > 0; s >>= 1) {
        if (tid < s) {
            float v2 = sv[tid + s]; int i2 = si[tid + s];
            if (v2 > sv[tid] || (v2 == sv[tid] && i2 < si[tid])) { sv[tid] = v2; si[tid] = i2; }
        }
        __syncthreads();
    }
    if (tid == 0) {
        int idx = si[0];
        out[row * 3 + 0] = doas[idx * 3 + 0];
        out[row * 3 + 1] = doas[idx * 3 + 1];
        out[row * 3 + 2] = doas[idx * 3 + 2];
    }
}

extern "C" void kernel_launch(void* const* d_in, const int* in_sizes, int n_in,
                              void* d_out, int out_size, void* d_ws, size_t ws_size,
                              hipStream_t stream) {
    const float* XXs  = (const float*)d_in[0];  // (4,250,513,2,36) f32
    const float* taus = (const float*)d_in[1];  // (2562,8) f32
    const float* doas = (const float*)d_in[2];  // (2562,3) f32
    float* ws     = (float*)d_ws;
    float* coefEO = ws + OFF_COEF;
    float* Tt     = ws + OFF_TT;
    float* G      = ws + OFF_G;
    float* Gp     = ws + OFF_GP;
    float* Ysp    = ws + OFF_YS;   // aliases Gp (consumed by k_reduceG first)

    k_coef   <<<F_BINS, 32, 0, stream>>>(coefEO);
    k_ttab   <<<dim3((D_PAD + 255) / 256, NPAIR), 256, 0, stream>>>(taus, Tt);
    k_stageA <<<dim3(M_TOTAL / NBT, FSPLIT), 256, 0, stream>>>(XXs, coefEO, Gp);
    k_reduceG<<<(M_TOTAL * K2 + 255) / 256, 256, 0, stream>>>(Gp, G);
    k_gemmB  <<<dim3(16, D_PAD / 128, KSPB), 256, 0, stream>>>(G, Tt, Ysp);
    k_argmax <<<M_TOTAL, 256, 0, stream>>>(Ysp, doas, (float*)d_out);
}

// Round 6
// 341.643 us; speedup vs baseline: 1.1348x; 1.1348x over previous
//
#include <hip/hip_runtime.h>
#include <math.h>

// SRP-PHAT via Chebyshev factorization (degree 32; tail ~1e-7 at z_max=14.67).
// G[bt, p*32+c] = sum_f Xnorm_{re|im}[bt,f,p] * coef_c(w_f*S), then
// Ys[bt,d] = sum_k G[bt,k] * Tt[k,d]. Diagonal mic pairs dropped.
// Round 6: stageA = fused normalize-on-load + register prefetch across the
// barrier (MLP fix for the 750 GB/s latency wall), whole-split coef in LDS,
// 128-thread blocks with 8 coefs/thread. gemmB = transposed Gt[k][bt] operand
// (via reduceG) -> all-b128 inner loop, 128x64 tiles, KSPB=2.

#define F_BINS  513
#define M_TOTAL 1000
#define D_TOTAL 2562
#define D_PAD   2688          // 42 * 64
#define NPAIR   28
#define NC      32
#define K2      (NPAIR * NC)  // 896
#define S_SCALE 4.67f         // |dtau| <= 4.665
#define NBT     4             // bt per stageA block
#define CNT     8             // f per stageA chunk
#define FSPLIT  6             // stageA f-splits
#define KSPB    2             // gemmB K-splits
#define KPS     448           // K2 / KSPB
#define BT_PAD  1024          // Gt row length (bt padded)

// ws layout (float offsets); total 8,718,464 floats = 34.9 MB
#define OFF_COEF 0
#define OFF_TT   16512
#define OFF_GT   (OFF_TT + (size_t)K2 * D_PAD)            // 2,424,960
#define OFF_GP   (OFF_GT + (size_t)K2 * BT_PAD)           // 3,342,464
#define OFF_YS   OFF_GP   // Ysp (2 planes = 5,376,000) aliases Gp (6 planes, same)

__device__ __constant__ int c_ptab[NPAIR] = {1,2,3,4,5,6,7, 9,10,11,12,13,14,
                                             16,17,18,19,20, 22,23,24,25,
                                             27,28,29, 31,32, 34};
__device__ __constant__ int c_i0[NPAIR] = {0,0,0,0,0,0,0, 1,1,1,1,1,1,
                                           2,2,2,2,2, 3,3,3,3, 4,4,4, 5,5, 6};
__device__ __constant__ int c_i1[NPAIR] = {1,2,3,4,5,6,7, 2,3,4,5,6,7,
                                           3,4,5,6,7, 4,5,6,7, 5,6,7, 6,7, 7};
// raw triu position -> off-diagonal pair index (-1 = diagonal)
__device__ __constant__ int c_inv[36] = {
    -1, 0, 1, 2, 3, 4, 5, 6,
    -1, 7, 8, 9,10,11,12,
    -1,13,14,15,16,17,
    -1,18,19,20,21,
    -1,22,23,24,
    -1,25,26,
    -1,27,
    -1};

// ---- coefEO[f][32]: c<16 -> cos-coeff a_{2c}(z_f); c>=16 -> sin b_{2c'+1} ---
__global__ void k_coef(float* __restrict__ coefEO) {
    __shared__ double sHC[NC][NC + 1];
    __shared__ double sHS[NC][NC + 1];
    const int f = blockIdx.x;
    const int t = threadIdx.x;          // 32 threads
    const double z = (double)f * (M_PI / 512.0) * (double)S_SCALE;
    double th = M_PI * (t + 0.5) / NC;
    double ct = cos(th);
    double hs, hc;
    sincos(z * ct, &hs, &hc);
    double cp = 1.0, cc = ct, c2 = 2.0 * ct;
    sHC[0][t] = hc;      sHS[0][t] = hs;
    sHC[1][t] = hc * cc; sHS[1][t] = hs * cc;
    for (int n = 2; n < NC; ++n) {
        double cn = c2 * cc - cp;
        cp = cc; cc = cn;
        sHC[n][t] = hc * cn;
        sHS[n][t] = hs * cn;
    }
    __syncthreads();
    const int n = (t < 16) ? 2 * t : 2 * (t - 16) + 1;
    double sum = 0.0;
    if (t < 16) { for (int j = 0; j < NC; ++j) sum += sHC[n][j]; }
    else        { for (int j = 0; j < NC; ++j) sum += sHS[n][j]; }
    double scale = (n == 0) ? (1.0 / NC) : (2.0 / NC);
    coefEO[f * 32 + t] = (float)(sum * scale);
}

// ---- Tt[p*32+c][d]: c<16 -> T_{2c}(u), c>=16 -> T_{2(c-16)+1}(u) -----------
__global__ void k_ttab(const float* __restrict__ taus, float* __restrict__ Tt) {
    const int d = blockIdx.x * 256 + threadIdx.x;
    const int p = blockIdx.y;
    if (d >= D_PAD) return;
    const bool live = d < D_TOTAL;
    const int dd = live ? d : 0;
    const float u = (taus[dd * 8 + c_i0[p]] - taus[dd * 8 + c_i1[p]]) * (1.0f / S_SCALE);
    float* base = Tt + (size_t)p * 32 * D_PAD + d;
    base[0] = live ? 1.f : 0.f;                       // n=0 -> c=0
    base[(size_t)16 * D_PAD] = live ? u : 0.f;        // n=1 -> c=16
    float tp = 1.f, tc = u;
    const float u2 = 2.f * u;
    for (int n = 2; n < NC; ++n) {
        float tn = u2 * tc - tp;
        tp = tc; tc = tn;
        int c = (n & 1) ? 16 + (n >> 1) : (n >> 1);
        base[(size_t)c * D_PAD] = live ? tn : 0.f;
    }
}

// ---- stage A: Gp[split][bt][p*32+c] ----------------------------------------
// 128 threads: p = t&31 (p>=28 dead), sel = t>>5: sel 0,1 -> Xr, c0 = sel*8;
// sel 2,3 -> Xi, c0 = 16+(sel-2)*8. 8 coefs & NBT bt per thread (32 acc).
// Per chunk: normalize current regs -> sXn4, issue next chunk's global float4
// loads (in flight across the barrier), compute from sXn4 + sCall.
#define NSLOT 3   // ceil(NBT*CNT*9 / 128)
__global__ __launch_bounds__(128, 3) void k_stageA(
    const float* __restrict__ XXs, const float* __restrict__ coefEO,
    float* __restrict__ Gp)
{
    __shared__ float4 sXn4[NBT][CNT / 4][64];  // [bt][fg][row(re 0..27, im 32..59)]
    __shared__ float  sCall[88][32];           // whole split's coef table
    const int t     = threadIdx.x;
    const int bt0   = blockIdx.x * NBT;
    const int split = blockIdx.y;
    const int fbeg  = (F_BINS * split) / FSPLIT;
    const int fend  = (F_BINS * (split + 1)) / FSPLIT;
    const int nf    = fend - fbeg;             // 85 or 86
    const int p   = t & 31;
    const int sel = t >> 5;
    const bool im = sel >= 2;
    const int row = (p < NPAIR ? p : NPAIR - 1) + (im ? 32 : 0);
    const int c0  = (sel & 1) * 8 + (im ? 16 : 0);

    // whole-split coef table (rows >= nf clamped to valid data; A=0 there)
    for (int e = t; e < 88 * 8; e += 128) {
        int fl = e >> 3, q = e & 7;
        int f  = fbeg + fl; if (f > F_BINS - 1) f = F_BINS - 1;
        *(float4*)&sCall[fl][q * 4] = *(const float4*)&coefEO[f * 32 + q * 4];
    }

    float acc[NBT][8] = {};
    float4 cur_re[NSLOT], cur_im[NSLOT], nxt_re[NSLOT], nxt_im[NSLOT];

    // issue global loads for chunk at fc (zero slots beyond range / tail)
    auto issue = [&](int fc, float4* vre, float4* vim) {
        const int cnt = min(CNT, fend - fc);
        #pragma unroll
        for (int s = 0; s < NSLOT; ++s) {
            int e = t + s * 128;
            float4 z4 = {0.f, 0.f, 0.f, 0.f};
            vre[s] = z4; vim[s] = z4;
            if (e < NBT * CNT * 9) {
                int q   = e % 9;
                int rbf = e / 9;
                int bt  = rbf / CNT;
                int fl  = rbf - bt * CNT;
                if (fl < cnt) {
                    const float* bp = XXs + (((size_t)(bt0 + bt) * F_BINS) + fc + fl) * 72;
                    vre[s] = *(const float4*)&bp[q * 4];
                    vim[s] = *(const float4*)&bp[36 + q * 4];
                }
            }
        }
    };

    issue(fbeg, cur_re, cur_im);

    for (int fc = fbeg; fc < fend; fc += CNT) {
        __syncthreads();   // previous compute done (also covers sCall on iter 0)
        // normalize current regs into sXn4 (zeros write zeros: 0 * 1e20 == 0)
        #pragma unroll
        for (int s = 0; s < NSLOT; ++s) {
            int e = t + s * 128;
            if (e >= NBT * CNT * 9) break;
            int q   = e % 9;
            int rbf = e / 9;
            int bt  = rbf / CNT;
            int fl  = rbf - bt * CNT;
            float* dst = (float*)&sXn4[bt][fl >> 2][0];
            const float* xr4 = (const float*)&cur_re[s];
            const float* xi4 = (const float*)&cur_im[s];
            #pragma unroll
            for (int j = 0; j < 4; ++j) {
                int pp = c_inv[q * 4 + j];
                if (pp >= 0) {
                    float xr = xr4[j], xi = xi4[j];
                    float inv = 1.f / (sqrtf(xr * xr + xi * xi) + 1e-20f);
                    dst[pp * 4 + (fl & 3)]        = xr * inv;
                    dst[(32 + pp) * 4 + (fl & 3)] = xi * inv;
                }
            }
        }
        if (fc + CNT < fend) issue(fc + CNT, nxt_re, nxt_im);  // prefetch
        __syncthreads();
        // compute: 2 f-groups x NBT bt x 4 f x 8 c
        const int cbase = fc - fbeg;
        #pragma unroll
        for (int fg = 0; fg < CNT / 4; ++fg) {
            float4 cjA[4], cjB[4];
            #pragma unroll
            for (int j = 0; j < 4; ++j) {
                cjA[j] = *(const float4*)&sCall[cbase + fg * 4 + j][c0];
                cjB[j] = *(const float4*)&sCall[cbase + fg * 4 + j][c0 + 4];
            }
            #pragma unroll
            for (int bt = 0; bt < NBT; ++bt) {
                float4 a4 = sXn4[bt][fg][row];
                float av[4] = {a4.x, a4.y, a4.z, a4.w};
                #pragma unroll
                for (int j = 0; j < 4; ++j) {
                    acc[bt][0] = fmaf(av[j], cjA[j].x, acc[bt][0]);
                    acc[bt][1] = fmaf(av[j], cjA[j].y, acc[bt][1]);
                    acc[bt][2] = fmaf(av[j], cjA[j].z, acc[bt][2]);
                    acc[bt][3] = fmaf(av[j], cjA[j].w, acc[bt][3]);
                    acc[bt][4] = fmaf(av[j], cjB[j].x, acc[bt][4]);
                    acc[bt][5] = fmaf(av[j], cjB[j].y, acc[bt][5]);
                    acc[bt][6] = fmaf(av[j], cjB[j].z, acc[bt][6]);
                    acc[bt][7] = fmaf(av[j], cjB[j].w, acc[bt][7]);
                }
            }
        }
        #pragma unroll
        for (int s = 0; s < NSLOT; ++s) { cur_re[s] = nxt_re[s]; cur_im[s] = nxt_im[s]; }
    }

    if (p < NPAIR) {
        float* gsp = Gp + (size_t)split * M_TOTAL * K2;
        #pragma unroll
        for (int bt = 0; bt < NBT; ++bt) {
            float* g = gsp + (size_t)(bt0 + bt) * K2 + p * 32 + c0;
            float4 v0 = {acc[bt][0], acc[bt][1], acc[bt][2], acc[bt][3]};
            float4 v1 = {acc[bt][4], acc[bt][5], acc[bt][6], acc[bt][7]};
            *(float4*)&g[0] = v0;
            *(float4*)&g[4] = v1;
        }
    }
}

// ---- reduce the 6 f-split partials into transposed, padded Gt[k][bt] -------
__global__ void k_reduceG(const float* __restrict__ Gp, float* __restrict__ Gt) {
    const int i = blockIdx.x * 256 + threadIdx.x;   // 917,504 threads total
    const size_t MK = (size_t)M_TOTAL * K2;
    if (i < (int)MK) {
        int bt = i / K2, k = i - bt * K2;
        float s = 0.f;
        #pragma unroll
        for (int pl = 0; pl < FSPLIT; ++pl) s += Gp[i + pl * MK];
        Gt[(size_t)k * BT_PAD + bt] = s;
    } else if (i < K2 * BT_PAD) {
        int j = i - (int)MK;
        int btp = j / K2, k = j - btp * K2;
        Gt[(size_t)k * BT_PAD + M_TOTAL + btp] = 0.f;   // zero-pad bt 1000..1023
    }
}

// ---- stage B: Ysp[split][1000][2688] partial of Gt^T @ Tt ------------------
#define BKB 32
__global__ __launch_bounds__(256, 4) void k_gemmB(
    const float* __restrict__ Gt, const float* __restrict__ Tt,
    float* __restrict__ Ysp)
{
    __shared__ float sA[BKB][136];   // [k][bt] — b128 reads, cf writes
    __shared__ float sB[BKB][68];
    const int t = threadIdx.x;
    const int row0 = blockIdx.x * 128;
    const int col0 = blockIdx.y * 64;
    const int koff = blockIdx.z * KPS;
    const int tx = t & 15;
    const int ty = t >> 4;
    float acc[8][4] = {};

    for (int k0 = 0; k0 < KPS; k0 += BKB) {
        __syncthreads();
        for (int e = t; e < 1024; e += 256) {   // A: 32k x 128bt, float4
            int kk = e >> 5, r4 = (e & 31) * 4;
            *(float4*)&sA[kk][r4] =
                *(const float4*)&Gt[(size_t)(koff + k0 + kk) * BT_PAD + row0 + r4];
        }
        for (int e = t; e < 512; e += 256) {    // B: 32k x 64d, float4
            int kk = e >> 4, c4 = (e & 15) * 4;
            *(float4*)&sB[kk][c4] =
                *(const float4*)&Tt[(size_t)(koff + k0 + kk) * D_PAD + col0 + c4];
        }
        __syncthreads();
        #pragma unroll 8
        for (int kk = 0; kk < BKB; ++kk) {
            float4 a0 = *(const float4*)&sA[kk][ty * 8];
            float4 a1 = *(const float4*)&sA[kk][ty * 8 + 4];
            float4 b  = *(const float4*)&sB[kk][tx * 4];
            float av[8] = {a0.x, a0.y, a0.z, a0.w, a1.x, a1.y, a1.z, a1.w};
            float bv[4] = {b.x, b.y, b.z, b.w};
            #pragma unroll
            for (int i = 0; i < 8; ++i)
                #pragma unroll
                for (int j = 0; j < 4; ++j)
                    acc[i][j] = fmaf(av[i], bv[j], acc[i][j]);
        }
    }
    float* yp = Ysp + (size_t)blockIdx.z * M_TOTAL * D_PAD;
    #pragma unroll
    for (int i = 0; i < 8; ++i) {
        int rg = row0 + ty * 8 + i;
        if (rg >= M_TOTAL) continue;
        float4 v = {acc[i][0], acc[i][1], acc[i][2], acc[i][3]};
        *(float4*)(yp + (size_t)rg * D_PAD + col0 + tx * 4) = v;
    }
}

// ---- argmax over summed K-split partials + doa gather ----------------------
__global__ __launch_bounds__(256) void k_argmax(
    const float* __restrict__ Ysp, const float* __restrict__ doas,
    float* __restrict__ out)
{
    __shared__ float sv[256];
    __shared__ int   si[256];
    const int row = blockIdx.x;
    const int tid = threadIdx.x;
    const float* y0 = Ysp + (size_t)row * D_PAD;
    const float* y1 = y0 + (size_t)M_TOTAL * D_PAD;
    float best = -INFINITY;
    int bi = D_TOTAL;
    for (int d = tid; d < D_TOTAL; d += 256) {
        float v = y0[d] + y1[d];
        if (v > best) { best = v; bi = d; }
    }
    sv[tid] = best; si[tid] = bi;
    __syncthreads();
    for (int s = 128; s > 0; s >>= 1) {
        if (tid < s) {
            float v2 = sv[tid + s]; int i2 = si[tid + s];
            if (v2 > sv[tid] || (v2 == sv[tid] && i2 < si[tid])) { sv[tid] = v2; si[tid] = i2; }
        }
        __syncthreads();
    }
    if (tid == 0) {
        int idx = si[0];
        out[row * 3 + 0] = doas[idx * 3 + 0];
        out[row * 3 + 1] = doas[idx * 3 + 1];
        out[row * 3 + 2] = doas[idx * 3 + 2];
    }
}

extern "C" void kernel_launch(void* const* d_in, const int* in_sizes, int n_in,
                              void* d_out, int out_size, void* d_ws, size_t ws_size,
                              hipStream_t stream) {
    const float* XXs  = (const float*)d_in[0];  // (4,250,513,2,36) f32
    const float* taus = (const float*)d_in[1];  // (2562,8) f32
    const float* doas = (const float*)d_in[2];  // (2562,3) f32
    float* ws     = (float*)d_ws;
    float* coefEO = ws + OFF_COEF;
    float* Tt     = ws + OFF_TT;
    float* Gt     = ws + OFF_GT;
    float* Gp     = ws + OFF_GP;
    float* Ysp    = ws + OFF_YS;   // aliases Gp (consumed by k_reduceG first)

    k_coef   <<<F_BINS, 32, 0, stream>>>(coefEO);
    k_ttab   <<<dim3((D_PAD + 255) / 256, NPAIR), 256, 0, stream>>>(taus, Tt);
    k_stageA <<<dim3(M_TOTAL / NBT, FSPLIT), 128, 0, stream>>>(XXs, coefEO, Gp);
    k_reduceG<<<(K2 * BT_PAD + 255) / 256, 256, 0, stream>>>(Gp, Gt);
    k_gemmB  <<<dim3(BT_PAD / 128, D_PAD / 64, KSPB), 256, 0, stream>>>(Gt, Tt, Ysp);
    k_argmax <<<M_TOTAL, 256, 0, stream>>>(Ysp, doas, (float*)d_out);
}